// Round 6
// baseline (455.907 us; speedup 1.0000x reference)
//
#include <hip/hip_runtime.h>
#include <math.h>

#define N_NODES 8192
#define CAP 128           // max neighbors/row; Binom(8192,0.004) mean~33 max~56, +self-loop
#define LRELU_ALPHA 0.2f

typedef float v4f __attribute__((ext_vector_type(4)));

// ---------- 8-row gemm on LDS A-tile, 256 thr, scalar weight reads (kA; K=256) ----------
template <int K>
__device__ __forceinline__ void gemm_from_lds(
    int r0, int t, const float* As, const float* __restrict__ W,
    const float* __restrict__ a, float* __restrict__ Wh, float* __restrict__ src,
    float* __restrict__ dst, float (*red)[4][2]) {
  int c = t & 127, half = t >> 7;
  float acc[4] = {0.f, 0.f, 0.f, 0.f};
  const float* Asl = As + (half * 4) * K;
#pragma unroll 2
  for (int k = 0; k < K; k += 4) {
    float w0 = W[(k + 0) * 128 + c];
    float w1 = W[(k + 1) * 128 + c];
    float w2 = W[(k + 2) * 128 + c];
    float w3 = W[(k + 3) * 128 + c];
#pragma unroll
    for (int r = 0; r < 4; r++) {
      float4 av = *(const float4*)&Asl[r * K + k];
      acc[r] += av.x * w0 + av.y * w1 + av.z * w2 + av.w * w3;
    }
  }
  float as = a[c], ad = a[128 + c];
  int wv_id = t >> 6, lane = t & 63;
#pragma unroll
  for (int r = 0; r < 4; r++) {
    int row = half * 4 + r;
    Wh[(size_t)(r0 + row) * 128 + c] = acc[r];
    float s = acc[r] * as, d = acc[r] * ad;
#pragma unroll
    for (int off = 32; off; off >>= 1) {
      s += __shfl_xor(s, off);
      d += __shfl_xor(d, off);
    }
    if (lane == 0) { red[wv_id][r][0] = s; red[wv_id][r][1] = d; }
  }
  __syncthreads();
  if (t < 8) {
    int wa = (t < 4) ? 0 : 2, rr = t & 3;
    src[r0 + t] = red[wa][rr][0] + red[wa + 1][rr][0];
    dst[r0 + t] = red[wa][rr][1] + red[wa + 1][rr][1];
  }
}

// ---------- 8-row gemm, 256 thr, K=128, PACKED-k weights W4[k4][128][4] (kB) ----------
// One coalesced b128 weight load per 4 k's (vs 4 scalar b32).
__device__ __forceinline__ void gemm128_w4(
    int r0, int t, const float* As, const float* __restrict__ W4,
    const float* __restrict__ a, float* __restrict__ Wh, float* __restrict__ src,
    float* __restrict__ dst, float (*red)[4][2]) {
  int c = t & 127, half = t >> 7;
  float acc[4] = {0.f, 0.f, 0.f, 0.f};
  const float* Asl = As + (half * 4) * 128;
#pragma unroll 4
  for (int k4 = 0; k4 < 32; k4++) {
    float4 w = *(const float4*)&W4[(k4 * 128 + c) * 4];
#pragma unroll
    for (int r = 0; r < 4; r++) {
      float4 av = *(const float4*)&Asl[r * 128 + 4 * k4];
      acc[r] += av.x * w.x + av.y * w.y + av.z * w.z + av.w * w.w;
    }
  }
  float as = a[c], ad = a[128 + c];
  int wv_id = t >> 6, lane = t & 63;
#pragma unroll
  for (int r = 0; r < 4; r++) {
    int row = half * 4 + r;
    Wh[(size_t)(r0 + row) * 128 + c] = acc[r];
    float s = acc[r] * as, d = acc[r] * ad;
#pragma unroll
    for (int off = 32; off; off >>= 1) {
      s += __shfl_xor(s, off);
      d += __shfl_xor(d, off);
    }
    if (lane == 0) { red[wv_id][r][0] = s; red[wv_id][r][1] = d; }
  }
  __syncthreads();
  if (t < 8) {
    int wa = (t < 4) ? 0 : 2, rr = t & 3;
    src[r0 + t] = red[wa][rr][0] + red[wa + 1][rr][0];
    dst[r0 + t] = red[wa][rr][1] + red[wa + 1][rr][1];
  }
}

// ---------- GAT aggregate, ONE node per 64-lane wave ----------
// Softmax in registers via shuffles. Gather weights/indices published to a
// per-wave jw[64] LDS table, then read back as 4 lane-uniform b128 broadcasts
// per 8 neighbors (replaces ~16 ds_bpermute). Lanes >= c hold (w=0, j=0) so
// padded rounds are harmless zero-weight broadcasts of row 0.
__device__ __forceinline__ float2 agg_node_wave(
    int i, int lane, const float* __restrict__ Wh, const float* __restrict__ src,
    const float* __restrict__ dst, const int* __restrict__ idxbuf,
    const int* __restrict__ counts, float2* jw) {
  int c = counts[i];
  float si = src[i];
  int j0 = 0, j1 = 0;
  float e0 = -1e30f, e1 = -1e30f;
  if (lane < c) {
    j0 = idxbuf[(size_t)i * CAP + lane];
    float xv = si + dst[j0];
    e0 = xv > 0.f ? xv : LRELU_ALPHA * xv;
  }
  if (lane + 64 < c) {
    j1 = idxbuf[(size_t)i * CAP + lane + 64];
    float xv = si + dst[j1];
    e1 = xv > 0.f ? xv : LRELU_ALPHA * xv;
  }
  float m = fmaxf(e0, e1);
#pragma unroll
  for (int off = 32; off; off >>= 1) m = fmaxf(m, __shfl_xor(m, off));
  float w0 = (lane < c) ? expf(e0 - m) : 0.f;
  float w1 = (lane + 64 < c) ? expf(e1 - m) : 0.f;
  float s = w0 + w1;
#pragma unroll
  for (int off = 32; off; off >>= 1) s += __shfl_xor(s, off);
  float inv = 1.f / s;
  jw[lane] = make_float2(w0, __int_as_float(j0));  // wave-local publish (lgkmcnt-ordered)
  const float2* Wh2 = (const float2*)Wh;  // row stride 64 float2
  float ax = 0.f, ay = 0.f;
  int cc = c < 64 ? c : 64;
  for (int k = 0; k < cc; k += 8) {  // 8 loads in flight; 4 uniform b128 broadcasts
    float4 p0 = *(const float4*)&jw[k];      // (w[k], j[k], w[k+1], j[k+1])
    float4 p1 = *(const float4*)&jw[k + 2];
    float4 p2 = *(const float4*)&jw[k + 4];
    float4 p3 = *(const float4*)&jw[k + 6];
    float2 v0 = Wh2[(size_t)(unsigned)__float_as_int(p0.y) * 64 + lane];
    float2 v1 = Wh2[(size_t)(unsigned)__float_as_int(p0.w) * 64 + lane];
    float2 v2 = Wh2[(size_t)(unsigned)__float_as_int(p1.y) * 64 + lane];
    float2 v3 = Wh2[(size_t)(unsigned)__float_as_int(p1.w) * 64 + lane];
    float2 v4 = Wh2[(size_t)(unsigned)__float_as_int(p2.y) * 64 + lane];
    float2 v5 = Wh2[(size_t)(unsigned)__float_as_int(p2.w) * 64 + lane];
    float2 v6 = Wh2[(size_t)(unsigned)__float_as_int(p3.y) * 64 + lane];
    float2 v7 = Wh2[(size_t)(unsigned)__float_as_int(p3.w) * 64 + lane];
    ax += p0.x * v0.x + p0.z * v1.x + p1.x * v2.x + p1.z * v3.x +
          p2.x * v4.x + p2.z * v5.x + p3.x * v6.x + p3.z * v7.x;
    ay += p0.x * v0.y + p0.z * v1.y + p1.x * v2.y + p1.z * v3.y +
          p2.x * v4.y + p2.z * v5.y + p3.x * v6.y + p3.z * v7.y;
  }
  if (c > 64) {  // overflow slot: not taken for this data (max c~57)
    for (int k = 64; k < c; k++) {
      float wk = __shfl(w1, k - 64);
      int jk = __shfl(j1, k - 64);
      float2 v = Wh2[(size_t)jk * 64 + lane];
      ax += wk * v.x; ay += wk * v.y;
    }
  }
  ax *= inv; ay *= inv;
  return make_float2(ax > 0.f ? ax : expf(ax) - 1.f,
                     ay > 0.f ? ay : expf(ay) - 1.f);
}

// ---------- GRU on LDS tiles: gates fused, 4 rows/thread, PACKED-k weights ----------
// WiT4/WhT4 layout [k4][384][4]: one coalesced b128 per gate-matrix per 4 k's.
// 192 weight-load instructions/thread (vs 768 scalar).
__device__ __forceinline__ void gru_tile(
    int i0, int t, const float* tile, const float* hs, const float* __restrict__ WiT4,
    const float* __restrict__ WhT4, const float* __restrict__ b_ih,
    const float* __restrict__ b_hh, float* __restrict__ outp) {
  int c = t & 127, half = t >> 7;
  const float* xsl = tile + half * 4 * 128;
  const float* hsl = hs + half * 4 * 128;
  float ai[3][4] = {{0.f}}, ah[3][4] = {{0.f}};
  for (int k4 = 0; k4 < 32; k4++) {
    float4 xv[4], hv[4];
#pragma unroll
    for (int r = 0; r < 4; r++) {
      xv[r] = *(const float4*)&xsl[r * 128 + 4 * k4];
      hv[r] = *(const float4*)&hsl[r * 128 + 4 * k4];
    }
#pragma unroll
    for (int g = 0; g < 3; g++) {
      float4 wi = *(const float4*)&WiT4[(k4 * 384 + g * 128 + c) * 4];
      float4 wh = *(const float4*)&WhT4[(k4 * 384 + g * 128 + c) * 4];
#pragma unroll
      for (int r = 0; r < 4; r++) {
        ai[g][r] += xv[r].x * wi.x + xv[r].y * wi.y + xv[r].z * wi.z + xv[r].w * wi.w;
        ah[g][r] += hv[r].x * wh.x + hv[r].y * wh.y + hv[r].z * wh.z + hv[r].w * wh.w;
      }
    }
  }
  float bi0 = b_ih[c], bi1 = b_ih[128 + c], bi2 = b_ih[256 + c];
  float bh0 = b_hh[c], bh1 = b_hh[128 + c], bh2 = b_hh[256 + c];
#pragma unroll
  for (int r = 0; r < 4; r++) {
    float rg = 1.f / (1.f + expf(-(ai[0][r] + bi0 + ah[0][r] + bh0)));
    float zg = 1.f / (1.f + expf(-(ai[1][r] + bi1 + ah[1][r] + bh1)));
    float n = tanhf(ai[2][r] + bi2 + rg * (ah[2][r] + bh2));
    outp[(size_t)(i0 + half * 4 + r) * 128 + c] =
        (1.f - zg) * n + zg * hsl[r * 128 + c];
  }
}

// ======= kernel A: gemm1 (blocks 0..1023) || weight repack (..1087) || adj scan (..9279) ==
// compute blocks first so they overlap the BW-bound scan from t=0.
__global__ __launch_bounds__(256) void kA(
    const float* __restrict__ adj, int* __restrict__ idxbuf, int* __restrict__ counts,
    const float* __restrict__ x, const float* __restrict__ W1, const float* __restrict__ a1,
    float* __restrict__ Wh1, float* __restrict__ src1, float* __restrict__ dst1,
    const float* __restrict__ Wi, const float* __restrict__ Whm, float* __restrict__ WiT4,
    float* __restrict__ WhT4, const float* __restrict__ W2, float* __restrict__ W2_4) {
  __shared__ float As[8 * 256];
  __shared__ float red[4][4][2];
  __shared__ int jn[CAP];
  __shared__ int cnt;
  int t = threadIdx.x, b = blockIdx.x;
  if (b < 1024) {
    const float4* Ab4 = (const float4*)(x + (size_t)b * 8 * 256);
    float4* As4 = (float4*)As;
#pragma unroll
    for (int l = t; l < 8 * 256 / 4; l += 256) As4[l] = Ab4[l];
    __syncthreads();
    gemm_from_lds<256>(b * 8, t, As, W1, a1, Wh1, src1, dst1, red);
  } else if (b < 1088) {
    // pack GRU weights: WiT4[k4][col][q] = Wi[col][4*k4+q]  (col 0..383, k 0..127)
    for (int n = (b - 1024) * 256 + t; n < 384 * 128; n += 64 * 256) {
      int col = n >> 7, k = n & 127;
      WiT4[((k >> 2) * 384 + col) * 4 + (k & 3)] = Wi[n];
      WhT4[((k >> 2) * 384 + col) * 4 + (k & 3)] = Whm[n];
    }
    // pack W2: W2_4[k4][c][q] = W2[4*k4+q][c]  (k 0..127, c 0..127)
    for (int n = (b - 1024) * 256 + t; n < 128 * 128; n += 64 * 256) {
      int k = n >> 7, c = n & 127;
      W2_4[((k >> 2) * 128 + c) * 4 + (k & 3)] = W2[n];
    }
  } else {
    int row = b - 1088;
    // ---- scan one adj row: 32 KB stream (CACHEABLE: adj ~= L3 size and is
    // re-read every iteration; nt hint was defeating Infinity-Cache retention) ----
    if (t == 0) cnt = 0;
    __syncthreads();
    const v4f* rowp = (const v4f*)(adj + (size_t)row * N_NODES);
    v4f v[8];
#pragma unroll
    for (int u = 0; u < 8; u++) v[u] = rowp[t + 256 * u];
#pragma unroll
    for (int u = 0; u < 8; u++) {
      int n = (v[u].x > 0.f) + (v[u].y > 0.f) + (v[u].z > 0.f) + (v[u].w > 0.f);
      if (n) {  // ~1.6% of threads
        int p = atomicAdd(&cnt, n);
        int j0 = (t + 256 * u) * 4;
        if (v[u].x > 0.f) { if (p < CAP) jn[p] = j0;     p++; }
        if (v[u].y > 0.f) { if (p < CAP) jn[p] = j0 + 1; p++; }
        if (v[u].z > 0.f) { if (p < CAP) jn[p] = j0 + 2; p++; }
        if (v[u].w > 0.f) { if (p < CAP) jn[p] = j0 + 3; p++; }
      }
    }
    __syncthreads();
    int c = cnt > CAP ? CAP : cnt;
    if (t < c) idxbuf[(size_t)row * CAP + t] = jn[t];
    if (t == 0) counts[row] = c;
  }
}

// ======= kernel B: agg1 for 8 nodes (4 waves x 2 rounds) -> LDS tile -> gemm2+srcdst2 ======
__global__ __launch_bounds__(256) void kB(
    const float* __restrict__ Wh1, const float* __restrict__ src1,
    const float* __restrict__ dst1, const int* __restrict__ idxbuf,
    const int* __restrict__ counts, const float* __restrict__ W2_4,
    const float* __restrict__ a2, float* __restrict__ Wh2, float* __restrict__ src2,
    float* __restrict__ dst2) {
  __shared__ float tile[8 * 128];
  __shared__ float red[4][4][2];
  __shared__ float2 jwb[4][64];
  int t = threadIdx.x, b = blockIdx.x;
  int i0 = b * 8;
  int wv = t >> 6, lane = t & 63;
  float2 r0 = agg_node_wave(i0 + wv, lane, Wh1, src1, dst1, idxbuf, counts, jwb[wv]);
  *(float2*)&tile[wv * 128 + 2 * lane] = r0;
  float2 r1 = agg_node_wave(i0 + 4 + wv, lane, Wh1, src1, dst1, idxbuf, counts, jwb[wv]);
  *(float2*)&tile[(4 + wv) * 128 + 2 * lane] = r1;
  __syncthreads();
  gemm128_w4(i0, t, tile, W2_4, a2, Wh2, src2, dst2, red);
}

// ======= kernel C: agg2 for 8 nodes -> LDS h_spat tile -> fused GRU ======
__global__ __launch_bounds__(256) void kC(
    const float* __restrict__ Wh2, const float* __restrict__ src2,
    const float* __restrict__ dst2, const int* __restrict__ idxbuf,
    const int* __restrict__ counts, const float* __restrict__ hprev,
    const float* __restrict__ WiT4, const float* __restrict__ WhT4,
    const float* __restrict__ b_ih, const float* __restrict__ b_hh, float* __restrict__ outp) {
  __shared__ float tile[8 * 128];
  __shared__ float hs[8 * 128];
  __shared__ float2 jwb[4][64];
  int t = threadIdx.x, b = blockIdx.x;
  int i0 = b * 8;
  ((float4*)hs)[t] = ((const float4*)(hprev + (size_t)i0 * 128))[t];
  int wv = t >> 6, lane = t & 63;
  float2 r0 = agg_node_wave(i0 + wv, lane, Wh2, src2, dst2, idxbuf, counts, jwb[wv]);
  *(float2*)&tile[wv * 128 + 2 * lane] = r0;
  float2 r1 = agg_node_wave(i0 + 4 + wv, lane, Wh2, src2, dst2, idxbuf, counts, jwb[wv]);
  *(float2*)&tile[(4 + wv) * 128 + 2 * lane] = r1;
  __syncthreads();
  gru_tile(i0, t, tile, hs, WiT4, WhT4, b_ih, b_hh, outp);
}

extern "C" void kernel_launch(void* const* d_in, const int* in_sizes, int n_in,
                              void* d_out, int out_size, void* d_ws, size_t ws_size,
                              hipStream_t stream) {
  const float* x     = (const float*)d_in[0];
  const float* adj   = (const float*)d_in[1];
  const float* hprev = (const float*)d_in[2];
  const float* W1    = (const float*)d_in[3];
  const float* a1    = (const float*)d_in[4];
  const float* W2    = (const float*)d_in[5];
  const float* a2    = (const float*)d_in[6];
  const float* Wi    = (const float*)d_in[7];
  const float* Whm   = (const float*)d_in[8];
  const float* b_ih  = (const float*)d_in[9];
  const float* b_hh  = (const float*)d_in[10];
  float* outp = (float*)d_out;

  char* p = (char*)d_ws;
  float* Wh1    = (float*)p; p += (size_t)N_NODES * 128 * 4;
  float* Wh2    = (float*)p; p += (size_t)N_NODES * 128 * 4;
  float* src1   = (float*)p; p += (size_t)N_NODES * 4;
  float* dst1   = (float*)p; p += (size_t)N_NODES * 4;
  float* src2   = (float*)p; p += (size_t)N_NODES * 4;
  float* dst2   = (float*)p; p += (size_t)N_NODES * 4;
  float* WiT4   = (float*)p; p += (size_t)384 * 128 * 4;
  float* WhT4   = (float*)p; p += (size_t)384 * 128 * 4;
  float* W2_4   = (float*)p; p += (size_t)128 * 128 * 4;
  int*   counts = (int*)p;   p += (size_t)N_NODES * 4;
  int*   idxbuf = (int*)p;   p += (size_t)N_NODES * CAP * 4;

  // A: gemm1 + weight repack first (compute), adj scan after (BW) -- they co-run
  kA<<<1024 + 64 + N_NODES, 256, 0, stream>>>(adj, idxbuf, counts, x, W1, a1, Wh1, src1, dst1,
                                              Wi, Whm, WiT4, WhT4, W2, W2_4);
  // B: agg1 (wave-per-node, jw-table gather) -> LDS x1 tile -> gemm2+srcdst2
  kB<<<N_NODES / 8, 256, 0, stream>>>(Wh1, src1, dst1, idxbuf, counts, W2_4, a2, Wh2, src2,
                                      dst2);
  // C: agg2 -> LDS h_spat tile -> fused-gate GRU (packed-k weights)
  kC<<<N_NODES / 8, 256, 0, stream>>>(Wh2, src2, dst2, idxbuf, counts, hprev, WiT4, WhT4, b_ih,
                                      b_hh, outp);
}

// Round 7
// 426.121 us; speedup vs baseline: 1.0699x; 1.0699x over previous
//
#include <hip/hip_runtime.h>
#include <math.h>

#define N_NODES 8192
#define CAP 128           // max neighbors/row; Binom(8192,0.004) mean~33 max~56, +self-loop
#define LRELU_ALPHA 0.2f

typedef float v4f __attribute__((ext_vector_type(4)));

// ---------- 8-row gemm on LDS A-tile, 256 thr, scalar weight reads (kA; K=256) ----------
template <int K>
__device__ __forceinline__ void gemm_from_lds(
    int r0, int t, const float* As, const float* __restrict__ W,
    const float* __restrict__ a, float* __restrict__ Wh, float* __restrict__ src,
    float* __restrict__ dst, float (*red)[4][2]) {
  int c = t & 127, half = t >> 7;
  float acc[4] = {0.f, 0.f, 0.f, 0.f};
  const float* Asl = As + (half * 4) * K;
#pragma unroll 2
  for (int k = 0; k < K; k += 4) {
    float w0 = W[(k + 0) * 128 + c];
    float w1 = W[(k + 1) * 128 + c];
    float w2 = W[(k + 2) * 128 + c];
    float w3 = W[(k + 3) * 128 + c];
#pragma unroll
    for (int r = 0; r < 4; r++) {
      float4 av = *(const float4*)&Asl[r * K + k];
      acc[r] += av.x * w0 + av.y * w1 + av.z * w2 + av.w * w3;
    }
  }
  float as = a[c], ad = a[128 + c];
  int wv_id = t >> 6, lane = t & 63;
#pragma unroll
  for (int r = 0; r < 4; r++) {
    int row = half * 4 + r;
    Wh[(size_t)(r0 + row) * 128 + c] = acc[r];
    float s = acc[r] * as, d = acc[r] * ad;
#pragma unroll
    for (int off = 32; off; off >>= 1) {
      s += __shfl_xor(s, off);
      d += __shfl_xor(d, off);
    }
    if (lane == 0) { red[wv_id][r][0] = s; red[wv_id][r][1] = d; }
  }
  __syncthreads();
  if (t < 8) {
    int wa = (t < 4) ? 0 : 2, rr = t & 3;
    src[r0 + t] = red[wa][rr][0] + red[wa + 1][rr][0];
    dst[r0 + t] = red[wa][rr][1] + red[wa + 1][rr][1];
  }
}

// ---------- 8-row gemm, 256 thr, K=128, PACKED-k weights W4[k4][128][4] (kB) ----------
// One coalesced b128 weight load per 4 k's (vs 4 scalar b32).
__device__ __forceinline__ void gemm128_w4(
    int r0, int t, const float* As, const float* __restrict__ W4,
    const float* __restrict__ a, float* __restrict__ Wh, float* __restrict__ src,
    float* __restrict__ dst, float (*red)[4][2]) {
  int c = t & 127, half = t >> 7;
  float acc[4] = {0.f, 0.f, 0.f, 0.f};
  const float* Asl = As + (half * 4) * 128;
#pragma unroll 4
  for (int k4 = 0; k4 < 32; k4++) {
    float4 w = *(const float4*)&W4[(k4 * 128 + c) * 4];
#pragma unroll
    for (int r = 0; r < 4; r++) {
      float4 av = *(const float4*)&Asl[r * 128 + 4 * k4];
      acc[r] += av.x * w.x + av.y * w.y + av.z * w.z + av.w * w.w;
    }
  }
  float as = a[c], ad = a[128 + c];
  int wv_id = t >> 6, lane = t & 63;
#pragma unroll
  for (int r = 0; r < 4; r++) {
    int row = half * 4 + r;
    Wh[(size_t)(r0 + row) * 128 + c] = acc[r];
    float s = acc[r] * as, d = acc[r] * ad;
#pragma unroll
    for (int off = 32; off; off >>= 1) {
      s += __shfl_xor(s, off);
      d += __shfl_xor(d, off);
    }
    if (lane == 0) { red[wv_id][r][0] = s; red[wv_id][r][1] = d; }
  }
  __syncthreads();
  if (t < 8) {
    int wa = (t < 4) ? 0 : 2, rr = t & 3;
    src[r0 + t] = red[wa][rr][0] + red[wa + 1][rr][0];
    dst[r0 + t] = red[wa][rr][1] + red[wa + 1][rr][1];
  }
}

// ---------- GAT aggregate, ONE node per 64-lane wave ----------
// Softmax in registers via shuffles. Gather weights/indices published to a
// per-wave jw[64] LDS table, then read back as 4 lane-uniform b128 broadcasts
// per 8 neighbors (replaces ~16 ds_bpermute). Lanes >= c hold (w=0, j=0) so
// padded rounds are harmless zero-weight broadcasts of row 0.
__device__ __forceinline__ float2 agg_node_wave(
    int i, int lane, const float* __restrict__ Wh, const float* __restrict__ src,
    const float* __restrict__ dst, const int* __restrict__ idxbuf,
    const int* __restrict__ counts, float2* jw) {
  int c = counts[i];
  float si = src[i];
  int j0 = 0, j1 = 0;
  float e0 = -1e30f, e1 = -1e30f;
  if (lane < c) {
    j0 = idxbuf[(size_t)i * CAP + lane];
    float xv = si + dst[j0];
    e0 = xv > 0.f ? xv : LRELU_ALPHA * xv;
  }
  if (lane + 64 < c) {
    j1 = idxbuf[(size_t)i * CAP + lane + 64];
    float xv = si + dst[j1];
    e1 = xv > 0.f ? xv : LRELU_ALPHA * xv;
  }
  float m = fmaxf(e0, e1);
#pragma unroll
  for (int off = 32; off; off >>= 1) m = fmaxf(m, __shfl_xor(m, off));
  float w0 = (lane < c) ? expf(e0 - m) : 0.f;
  float w1 = (lane + 64 < c) ? expf(e1 - m) : 0.f;
  float s = w0 + w1;
#pragma unroll
  for (int off = 32; off; off >>= 1) s += __shfl_xor(s, off);
  float inv = 1.f / s;
  jw[lane] = make_float2(w0, __int_as_float(j0));  // wave-local publish (lgkmcnt-ordered)
  const float2* Wh2 = (const float2*)Wh;  // row stride 64 float2
  float ax = 0.f, ay = 0.f;
  int cc = c < 64 ? c : 64;
  for (int k = 0; k < cc; k += 8) {  // 8 loads in flight; 4 uniform b128 broadcasts
    float4 p0 = *(const float4*)&jw[k];      // (w[k], j[k], w[k+1], j[k+1])
    float4 p1 = *(const float4*)&jw[k + 2];
    float4 p2 = *(const float4*)&jw[k + 4];
    float4 p3 = *(const float4*)&jw[k + 6];
    float2 v0 = Wh2[(size_t)(unsigned)__float_as_int(p0.y) * 64 + lane];
    float2 v1 = Wh2[(size_t)(unsigned)__float_as_int(p0.w) * 64 + lane];
    float2 v2 = Wh2[(size_t)(unsigned)__float_as_int(p1.y) * 64 + lane];
    float2 v3 = Wh2[(size_t)(unsigned)__float_as_int(p1.w) * 64 + lane];
    float2 v4 = Wh2[(size_t)(unsigned)__float_as_int(p2.y) * 64 + lane];
    float2 v5 = Wh2[(size_t)(unsigned)__float_as_int(p2.w) * 64 + lane];
    float2 v6 = Wh2[(size_t)(unsigned)__float_as_int(p3.y) * 64 + lane];
    float2 v7 = Wh2[(size_t)(unsigned)__float_as_int(p3.w) * 64 + lane];
    ax += p0.x * v0.x + p0.z * v1.x + p1.x * v2.x + p1.z * v3.x +
          p2.x * v4.x + p2.z * v5.x + p3.x * v6.x + p3.z * v7.x;
    ay += p0.x * v0.y + p0.z * v1.y + p1.x * v2.y + p1.z * v3.y +
          p2.x * v4.y + p2.z * v5.y + p3.x * v6.y + p3.z * v7.y;
  }
  if (c > 64) {  // overflow slot: not taken for this data (max c~57)
    for (int k = 64; k < c; k++) {
      float wk = __shfl(w1, k - 64);
      int jk = __shfl(j1, k - 64);
      float2 v = Wh2[(size_t)jk * 64 + lane];
      ax += wk * v.x; ay += wk * v.y;
    }
  }
  ax *= inv; ay *= inv;
  return make_float2(ax > 0.f ? ax : expf(ax) - 1.f,
                     ay > 0.f ? ay : expf(ay) - 1.f);
}

// ---------- GRU on LDS tiles: gates fused, 4 rows/thread, PACKED-k weights ----------
// WiT4/WhT4 layout [k4][384][4]: one coalesced b128 per gate-matrix per 4 k's.
// 192 weight-load instructions/thread (vs 768 scalar).
__device__ __forceinline__ void gru_tile(
    int i0, int t, const float* tile, const float* hs, const float* __restrict__ WiT4,
    const float* __restrict__ WhT4, const float* __restrict__ b_ih,
    const float* __restrict__ b_hh, float* __restrict__ outp) {
  int c = t & 127, half = t >> 7;
  const float* xsl = tile + half * 4 * 128;
  const float* hsl = hs + half * 4 * 128;
  float ai[3][4] = {{0.f}}, ah[3][4] = {{0.f}};
  for (int k4 = 0; k4 < 32; k4++) {
    float4 xv[4], hv[4];
#pragma unroll
    for (int r = 0; r < 4; r++) {
      xv[r] = *(const float4*)&xsl[r * 128 + 4 * k4];
      hv[r] = *(const float4*)&hsl[r * 128 + 4 * k4];
    }
#pragma unroll
    for (int g = 0; g < 3; g++) {
      float4 wi = *(const float4*)&WiT4[(k4 * 384 + g * 128 + c) * 4];
      float4 wh = *(const float4*)&WhT4[(k4 * 384 + g * 128 + c) * 4];
#pragma unroll
      for (int r = 0; r < 4; r++) {
        ai[g][r] += xv[r].x * wi.x + xv[r].y * wi.y + xv[r].z * wi.z + xv[r].w * wi.w;
        ah[g][r] += hv[r].x * wh.x + hv[r].y * wh.y + hv[r].z * wh.z + hv[r].w * wh.w;
      }
    }
  }
  float bi0 = b_ih[c], bi1 = b_ih[128 + c], bi2 = b_ih[256 + c];
  float bh0 = b_hh[c], bh1 = b_hh[128 + c], bh2 = b_hh[256 + c];
#pragma unroll
  for (int r = 0; r < 4; r++) {
    float rg = 1.f / (1.f + expf(-(ai[0][r] + bi0 + ah[0][r] + bh0)));
    float zg = 1.f / (1.f + expf(-(ai[1][r] + bi1 + ah[1][r] + bh1)));
    float n = tanhf(ai[2][r] + bi2 + rg * (ah[2][r] + bh2));
    outp[(size_t)(i0 + half * 4 + r) * 128 + c] =
        (1.f - zg) * n + zg * hsl[r * 128 + c];
  }
}

// ======= kernel A: gemm1 (blocks 0..1023) || weight repack (..1087) || adj scan (..9279) ==
// compute blocks first so they overlap the BW-bound scan from t=0.
__global__ __launch_bounds__(256) void kA(
    const float* __restrict__ adj, int* __restrict__ idxbuf, int* __restrict__ counts,
    const float* __restrict__ x, const float* __restrict__ W1, const float* __restrict__ a1,
    float* __restrict__ Wh1, float* __restrict__ src1, float* __restrict__ dst1,
    const float* __restrict__ Wi, const float* __restrict__ Whm, float* __restrict__ WiT4,
    float* __restrict__ WhT4, const float* __restrict__ W2, float* __restrict__ W2_4) {
  __shared__ float As[8 * 256];
  __shared__ float red[4][4][2];
  __shared__ int jn[CAP];
  __shared__ int cnt;
  int t = threadIdx.x, b = blockIdx.x;
  if (b < 1024) {
    const float4* Ab4 = (const float4*)(x + (size_t)b * 8 * 256);
    float4* As4 = (float4*)As;
#pragma unroll
    for (int l = t; l < 8 * 256 / 4; l += 256) As4[l] = Ab4[l];
    __syncthreads();
    gemm_from_lds<256>(b * 8, t, As, W1, a1, Wh1, src1, dst1, red);
  } else if (b < 1088) {
    // pack GRU weights: WiT4[k4][col][q] = Wi[col][4*k4+q]  (col 0..383, k 0..127)
    for (int n = (b - 1024) * 256 + t; n < 384 * 128; n += 64 * 256) {
      int col = n >> 7, k = n & 127;
      WiT4[((k >> 2) * 384 + col) * 4 + (k & 3)] = Wi[n];
      WhT4[((k >> 2) * 384 + col) * 4 + (k & 3)] = Whm[n];
    }
    // pack W2: W2_4[k4][c][q] = W2[4*k4+q][c]  (k 0..127, c 0..127)
    for (int n = (b - 1024) * 256 + t; n < 128 * 128; n += 64 * 256) {
      int k = n >> 7, c = n & 127;
      W2_4[((k >> 2) * 128 + c) * 4 + (k & 3)] = W2[n];
    }
  } else {
    int row = b - 1088;
    // ---- scan one adj row: 32 KB NONTEMPORAL stream (proven: cacheable loads
    // thrash L3 and cost +28 us end-to-end; nt keeps Wh/weights/idxbuf resident) ----
    if (t == 0) cnt = 0;
    __syncthreads();
    const v4f* rowp = (const v4f*)(adj + (size_t)row * N_NODES);
    v4f v[8];
#pragma unroll
    for (int u = 0; u < 8; u++) v[u] = __builtin_nontemporal_load(rowp + t + 256 * u);
#pragma unroll
    for (int u = 0; u < 8; u++) {
      int n = (v[u].x > 0.f) + (v[u].y > 0.f) + (v[u].z > 0.f) + (v[u].w > 0.f);
      if (n) {  // ~1.6% of threads
        int p = atomicAdd(&cnt, n);
        int j0 = (t + 256 * u) * 4;
        if (v[u].x > 0.f) { if (p < CAP) jn[p] = j0;     p++; }
        if (v[u].y > 0.f) { if (p < CAP) jn[p] = j0 + 1; p++; }
        if (v[u].z > 0.f) { if (p < CAP) jn[p] = j0 + 2; p++; }
        if (v[u].w > 0.f) { if (p < CAP) jn[p] = j0 + 3; p++; }
      }
    }
    __syncthreads();
    int c = cnt > CAP ? CAP : cnt;
    if (t < c) idxbuf[(size_t)row * CAP + t] = jn[t];
    if (t == 0) counts[row] = c;
  }
}

// ======= kernel B: agg1 for 8 nodes (4 waves x 2 rounds) -> LDS tile -> gemm2+srcdst2 ======
__global__ __launch_bounds__(256) void kB(
    const float* __restrict__ Wh1, const float* __restrict__ src1,
    const float* __restrict__ dst1, const int* __restrict__ idxbuf,
    const int* __restrict__ counts, const float* __restrict__ W2_4,
    const float* __restrict__ a2, float* __restrict__ Wh2, float* __restrict__ src2,
    float* __restrict__ dst2) {
  __shared__ float tile[8 * 128];
  __shared__ float red[4][4][2];
  __shared__ float2 jwb[4][64];
  int t = threadIdx.x, b = blockIdx.x;
  int i0 = b * 8;
  int wv = t >> 6, lane = t & 63;
  float2 r0 = agg_node_wave(i0 + wv, lane, Wh1, src1, dst1, idxbuf, counts, jwb[wv]);
  *(float2*)&tile[wv * 128 + 2 * lane] = r0;
  float2 r1 = agg_node_wave(i0 + 4 + wv, lane, Wh1, src1, dst1, idxbuf, counts, jwb[wv]);
  *(float2*)&tile[(4 + wv) * 128 + 2 * lane] = r1;
  __syncthreads();
  gemm128_w4(i0, t, tile, W2_4, a2, Wh2, src2, dst2, red);
}

// ======= kernel C: agg2 for 8 nodes -> LDS h_spat tile -> fused GRU ======
__global__ __launch_bounds__(256) void kC(
    const float* __restrict__ Wh2, const float* __restrict__ src2,
    const float* __restrict__ dst2, const int* __restrict__ idxbuf,
    const int* __restrict__ counts, const float* __restrict__ hprev,
    const float* __restrict__ WiT4, const float* __restrict__ WhT4,
    const float* __restrict__ b_ih, const float* __restrict__ b_hh, float* __restrict__ outp) {
  __shared__ float tile[8 * 128];
  __shared__ float hs[8 * 128];
  __shared__ float2 jwb[4][64];
  int t = threadIdx.x, b = blockIdx.x;
  int i0 = b * 8;
  ((float4*)hs)[t] = ((const float4*)(hprev + (size_t)i0 * 128))[t];
  int wv = t >> 6, lane = t & 63;
  float2 r0 = agg_node_wave(i0 + wv, lane, Wh2, src2, dst2, idxbuf, counts, jwb[wv]);
  *(float2*)&tile[wv * 128 + 2 * lane] = r0;
  float2 r1 = agg_node_wave(i0 + 4 + wv, lane, Wh2, src2, dst2, idxbuf, counts, jwb[wv]);
  *(float2*)&tile[(4 + wv) * 128 + 2 * lane] = r1;
  __syncthreads();
  gru_tile(i0, t, tile, hs, WiT4, WhT4, b_ih, b_hh, outp);
}

extern "C" void kernel_launch(void* const* d_in, const int* in_sizes, int n_in,
                              void* d_out, int out_size, void* d_ws, size_t ws_size,
                              hipStream_t stream) {
  const float* x     = (const float*)d_in[0];
  const float* adj   = (const float*)d_in[1];
  const float* hprev = (const float*)d_in[2];
  const float* W1    = (const float*)d_in[3];
  const float* a1    = (const float*)d_in[4];
  const float* W2    = (const float*)d_in[5];
  const float* a2    = (const float*)d_in[6];
  const float* Wi    = (const float*)d_in[7];
  const float* Whm   = (const float*)d_in[8];
  const float* b_ih  = (const float*)d_in[9];
  const float* b_hh  = (const float*)d_in[10];
  float* outp = (float*)d_out;

  char* p = (char*)d_ws;
  float* Wh1    = (float*)p; p += (size_t)N_NODES * 128 * 4;
  float* Wh2    = (float*)p; p += (size_t)N_NODES * 128 * 4;
  float* src1   = (float*)p; p += (size_t)N_NODES * 4;
  float* dst1   = (float*)p; p += (size_t)N_NODES * 4;
  float* src2   = (float*)p; p += (size_t)N_NODES * 4;
  float* dst2   = (float*)p; p += (size_t)N_NODES * 4;
  float* WiT4   = (float*)p; p += (size_t)384 * 128 * 4;
  float* WhT4   = (float*)p; p += (size_t)384 * 128 * 4;
  float* W2_4   = (float*)p; p += (size_t)128 * 128 * 4;
  int*   counts = (int*)p;   p += (size_t)N_NODES * 4;
  int*   idxbuf = (int*)p;   p += (size_t)N_NODES * CAP * 4;

  // A: gemm1 + weight repack first (compute), adj scan after (BW) -- they co-run
  kA<<<1024 + 64 + N_NODES, 256, 0, stream>>>(adj, idxbuf, counts, x, W1, a1, Wh1, src1, dst1,
                                              Wi, Whm, WiT4, WhT4, W2, W2_4);
  // B: agg1 (wave-per-node, jw-table gather) -> LDS x1 tile -> gemm2+srcdst2
  kB<<<N_NODES / 8, 256, 0, stream>>>(Wh1, src1, dst1, idxbuf, counts, W2_4, a2, Wh2, src2,
                                      dst2);
  // C: agg2 -> LDS h_spat tile -> fused-gate GRU (packed-k weights)
  kC<<<N_NODES / 8, 256, 0, stream>>>(Wh2, src2, dst2, idxbuf, counts, hprev, WiT4, WhT4, b_ih,
                                      b_hh, outp);
}